// Round 7
// baseline (807.777 us; speedup 1.0000x reference)
//
#include <hip/hip_runtime.h>
#include <hip/hip_bf16.h>

typedef unsigned short u16;
typedef unsigned int u32;
typedef __attribute__((ext_vector_type(4))) float f32x4;
typedef __attribute__((ext_vector_type(8))) short short8;
typedef __attribute__((ext_vector_type(4))) unsigned short u16x4;
typedef __attribute__((ext_vector_type(2))) unsigned int u32x2;
typedef __attribute__((ext_vector_type(4))) unsigned int u32x4;

// B=32, T=64, I=H=512, V=32000, G=4H=2048, M=T*B=2048
#define LSTM_NBLK 8

static __device__ __forceinline__ u16 f2bf(float f) {
  union { float f; unsigned u; } v; v.f = f;
  unsigned r = v.u + 0x7FFFu + ((v.u >> 16) & 1u);
  return (u16)(r >> 16);
}

static __device__ __forceinline__ void gload_lds16(const void* g, void* l) {
  __builtin_amdgcn_global_load_lds(
      (const __attribute__((address_space(1))) unsigned int*)g,
      (__attribute__((address_space(3))) unsigned int*)l, 16, 0, 0);
}

// --- L3-coherent (cross-XCD) access helpers: bypass L1/L2 ---
static __device__ __forceinline__ u32x4 ld_b128u_sc(const u32* p) {
  u32x4 r;
  asm volatile("global_load_dwordx4 %0, %1, off sc0 sc1"
               : "=v"(r) : "v"(p) : "memory");
  return r;
}
static __device__ __forceinline__ void st_b128u_sc(void* p, u32x4 v) {
  asm volatile("global_store_dwordx4 %0, %1, off sc0 sc1"
               :: "v"(p), "v"(v) : "memory");
}
static __device__ __forceinline__ void waitcnt0() {
  asm volatile("s_waitcnt vmcnt(0)" ::: "memory");
  __builtin_amdgcn_sched_barrier(0);
}

// ---------------- prep: casts + transpose + tagged slot0 + h2 slot0 ----------------
// htag slot layout (16384 u32 = 64KB): [producer blk 0..7][b 0..31][jl 0..63],
// u32 = {tag:16, bf16 payload:16}; global j = blk*64 + jl.
__global__ void prep_kernel(const float* __restrict__ iseq, const float* __restrict__ h0,
                            const float* __restrict__ wih, const float* __restrict__ whh,
                            const float* __restrict__ wout,
                            u16* __restrict__ wout_bf, u16* __restrict__ wih_bf,
                            u16* __restrict__ whh_bf, u16* __restrict__ ax,
                            u32* __restrict__ htag, u32* __restrict__ h2u) {
  const int S0 = 4096000;                 // Wout /4
  const int S1 = S0 + 262144;             // Wih /4
  const int S2 = S1 + 262144;             // Whh /4
  const int S3 = S2 + 262144;             // ax /4
  const int S4 = S3 + 4096;               // htag slot 0 (16384 u32 /4)
  const int S5 = S4 + 258048;             // clear tags of slots 1..63
  const int S6 = S5 + 2048;               // h2 slot 0 (8192 u32 /4)
  int u = blockIdx.x * blockDim.x + threadIdx.x;
  int stride = gridDim.x * blockDim.x;
  for (; u < S6; u += stride) {
    if (u < S0) {
      int e = u * 4; f32x4 v = *(const f32x4*)(wout + e);
      u16x4 o; o[0]=f2bf(v[0]); o[1]=f2bf(v[1]); o[2]=f2bf(v[2]); o[3]=f2bf(v[3]);
      *(u16x4*)(wout_bf + e) = o;
    } else if (u < S1) {
      int e = (u - S0) * 4; f32x4 v = *(const f32x4*)(wih + e);
      u16x4 o; o[0]=f2bf(v[0]); o[1]=f2bf(v[1]); o[2]=f2bf(v[2]); o[3]=f2bf(v[3]);
      *(u16x4*)(wih_bf + e) = o;
    } else if (u < S2) {
      int e = (u - S1) * 4; f32x4 v = *(const f32x4*)(whh + e);
      u16x4 o; o[0]=f2bf(v[0]); o[1]=f2bf(v[1]); o[2]=f2bf(v[2]); o[3]=f2bf(v[3]);
      *(u16x4*)(whh_bf + e) = o;
    } else if (u < S3) {
      // A_x[m= t*32+b][k] = iseq[b][t][k]
      int e = (u - S2) * 4; int m = e >> 9; int k = e & 511;
      int b = m & 31; int t = m >> 5;
      f32x4 v = *(const f32x4*)(iseq + ((b * 64 + t) << 9) + k);
      u16x4 o; o[0]=f2bf(v[0]); o[1]=f2bf(v[1]); o[2]=f2bf(v[2]); o[3]=f2bf(v[3]);
      *(u16x4*)(ax + e) = o;
    } else if (u < S4) {
      // htag slot 0 = {tag=1, bf16(h0)} in producer-contiguous layout
      int e = (u - S3) * 4;            // u32 index, 4-aligned
      int blkp = e >> 11;
      int r = e & 2047;
      int b = r >> 6;
      int jl = r & 63;                 // 4-aligned
      f32x4 v = *(const f32x4*)(h0 + b * 512 + blkp * 64 + jl);
      u32x4 o;
      o[0] = (1u << 16) | f2bf(v[0]); o[1] = (1u << 16) | f2bf(v[1]);
      o[2] = (1u << 16) | f2bf(v[2]); o[3] = (1u << 16) | f2bf(v[3]);
      *(u32x4*)(htag + e) = o;
    } else if (u < S5) {
      // clear tags of slots 1..63
      int e = (u - S4) * 4;
      u32x4 z = {0u, 0u, 0u, 0u};
      *(u32x4*)(htag + 16384 + e) = z;
    } else {
      // h2 slot 0 = bf16(h0) packed pairs, plain [32][512]
      int v = (u - S5) * 4;               // u32 index, 4 per iter
      int e = v * 2;                      // f32 element index
      f32x4 x0 = *(const f32x4*)(h0 + e);
      f32x4 x1 = *(const f32x4*)(h0 + e + 4);
      u32x4 o;
      o[0] = (((u32)f2bf(x0[1])) << 16) | (u32)f2bf(x0[0]);
      o[1] = (((u32)f2bf(x0[3])) << 16) | (u32)f2bf(x0[2]);
      o[2] = (((u32)f2bf(x1[1])) << 16) | (u32)f2bf(x1[0]);
      o[3] = (((u32)f2bf(x1[3])) << 16) | (u32)f2bf(x1[2]);
      *(u32x4*)(h2u + v) = o;
    }
  }
}

// ---------------- generic C = A*Bw^T + bias GEMM ----------------
// A: [2048][512] bf16 row-major (remap=0) or h2-slot layout (remap=1),
// Bw: [N][512] bf16 row-major, C: [2048][N] f32
__global__ __launch_bounds__(256, 2) void gemm_bt(
    const u16* __restrict__ A, const u16* __restrict__ Bw,
    float* __restrict__ C, const float* __restrict__ bias1,
    const float* __restrict__ bias2, int N, int remap) {
  __shared__ u16 As[2][8192];
  __shared__ u16 Bs[2][8192];
  const int tid = threadIdx.x;
  const int w = tid >> 6, l = tid & 63;
  const int wr = w >> 1, wc = w & 1;
  const int tm = blockIdx.y * 128, tn = blockIdx.x * 128;

  f32x4 acc[4][4];
#pragma unroll
  for (int i = 0; i < 4; ++i)
#pragma unroll
    for (int j = 0; j < 4; ++j) acc[i][j] = (f32x4){0.f, 0.f, 0.f, 0.f};

  auto stage = [&](int buf, int kt) {
#pragma unroll
    for (int i = 0; i < 4; ++i) {
      int r = (w * 4 + i) * 8 + (l >> 3);
      int c16 = (l & 7) ^ (r & 7);  // pre-swizzled source column
      int rowm = tm + r;
      const u16* srca;
      if (remap) {
        // logical A row m -> h_t[b] : slot (m&63)+1, row m>>6
        srca = A + ((rowm & 63) + 1) * 16384 + (rowm >> 6) * 512 + kt * 64 + c16 * 8;
      } else {
        srca = A + rowm * 512 + kt * 64 + c16 * 8;
      }
      gload_lds16(srca, &As[buf][(w * 4 + i) * 512]);
      const u16* srcb = Bw + (tn + r) * 512 + kt * 64 + c16 * 8;
      gload_lds16(srcb, &Bs[buf][(w * 4 + i) * 512]);
    }
  };

  stage(0, 0);
  int buf = 0;
  for (int kt = 0; kt < 8; ++kt) {
    __syncthreads();
    if (kt < 7) stage(buf ^ 1, kt + 1);
#pragma unroll
    for (int kk = 0; kk < 2; ++kk) {
      short8 af[4], bfr[4];
#pragma unroll
      for (int mi = 0; mi < 4; ++mi) {
        int row = wr * 64 + mi * 16 + (l & 15);
        int s = (kk * 4 + (l >> 4)) ^ (row & 7);
        af[mi] = *(const short8*)&As[buf][row * 64 + s * 8];
      }
#pragma unroll
      for (int ni = 0; ni < 4; ++ni) {
        int row = wc * 64 + ni * 16 + (l & 15);
        int s = (kk * 4 + (l >> 4)) ^ (row & 7);
        bfr[ni] = *(const short8*)&Bs[buf][row * 64 + s * 8];
      }
#pragma unroll
      for (int mi = 0; mi < 4; ++mi)
#pragma unroll
        for (int ni = 0; ni < 4; ++ni)
          acc[mi][ni] = __builtin_amdgcn_mfma_f32_16x16x32_bf16(
              af[mi], bfr[ni], acc[mi][ni], 0, 0, 0);
    }
    buf ^= 1;
  }

#pragma unroll
  for (int ni = 0; ni < 4; ++ni) {
    int gcol = tn + wc * 64 + ni * 16 + (l & 15);
    float bv = 0.f;
    if (bias1) bv += bias1[gcol];
    if (bias2) bv += bias2[gcol];
#pragma unroll
    for (int mi = 0; mi < 4; ++mi) {
      int grow0 = tm + wr * 64 + mi * 16 + ((l >> 4) << 2);
      f32x4 a = acc[mi][ni];
#pragma unroll
      for (int q = 0; q < 4; ++q) {
        C[(long long)(grow0 + q) * N + gcol] = a[q] + bv;
      }
    }
  }
}

// ---------------- persistent LSTM recurrence (1-hop tagged exchange) ----------
// 8 blocks x 1024 threads (16 waves). Wave owns 4 j-cols => 16 W_hh rows in
// registers; cell state in registers. Per step: each thread polls a PRIVATE
// 64B of the tagged slot (per-u32 tag, per-lane early exit), stages payloads
// into XOR-swizzled LDS, barrier, MFMA, pointwise -> hloc, barrier, publish:
// contiguous 8KB tagged dwordx4 sc-stores (fire-and-forget, no drain, no
// flags) + plain h2 copy for gemm2. Own slice short-circuits via LDS.
__global__ __launch_bounds__(1024, 1) void lstm_persist(
    const u16* __restrict__ whh, const float* __restrict__ xg,
    u16* __restrict__ h2, u32* __restrict__ htag) {
  __shared__ u16 hbuf[32 * 512];   // 32 KB, [b][swizzled k-blocks]
  __shared__ u16 hloc[32 * 64];    // 4 KB, [b][jl] block's own h slice
  const int tid = threadIdx.x;
  const int w = tid >> 6, l = tid & 63;
  const int blk = blockIdx.x;                      // 0..7
  const int j0 = blk * 64 + w * 4;                 // wave's 4 h-columns
  const int c = l & 15;
  const int wrow = (c >> 2) * 512 + j0 + (c & 3);  // W_hh row == gate column
  const int ko = (l >> 4) * 8;
  u32* h2u = (u32*)h2;

  // resident weights: 16 x short8 = 64 VGPRs
  short8 bfr[16];
  const u16* wp = whh + wrow * 512 + ko;
#pragma unroll
  for (int kt = 0; kt < 16; ++kt) bfr[kt] = *(const short8*)(wp + kt * 32);

  const int rq = (l >> 4) * 4;
  const int jj = l & 3;
  const int b0 = l & 15, b1 = 16 + (l & 15);
  const int s0 = b0 & 7;

  // sweep mapping: thread owns 16 u32 (64B) of the 16384-u32 slot
  const int sw_base = tid * 16;
  const int sw_blkp = tid >> 7;                    // producer 0..7
  const int sw_b = (sw_base & 2047) >> 6;          // batch row 0..31
  const int sw_jl = sw_base & 63;                  // 0/16/32/48
  const int sw_x0 = (sw_blkp * 64 + sw_jl) >> 3;   // col-blocks x0, x0+1
  const int sw_swz = sw_b & 7;
  const bool own = (sw_blkp == blk);

  // publish mapping: 512 threads per group, element (pb, pj4..pj4+3)
  const int pb = (tid & 511) >> 4;                 // 0..31
  const int pj4 = (tid & 15) * 4;                  // 0..60

  float creg[2][4];
#pragma unroll
  for (int mt = 0; mt < 2; ++mt)
#pragma unroll
    for (int q = 0; q < 4; ++q) creg[mt][q] = 0.f;

  for (int it = 0; it < 64; ++it) {
    // ---- (A) acquire h_prev: own slice from LDS, rest via private-poll ----
    short8 plo, phi;
    if (own && it > 0) {
      plo = *(const short8*)&hloc[sw_b * 64 + sw_jl];
      phi = *(const short8*)&hloc[sw_b * 64 + sw_jl + 8];
    } else {
      const u32* src = htag + it * 16384 + sw_base;
      const unsigned want = (unsigned)(it + 1);
      u32x4 a0, a1, a2, a3;
      for (;;) {
        a0 = ld_b128u_sc(src + 0);
        a1 = ld_b128u_sc(src + 4);
        a2 = ld_b128u_sc(src + 8);
        a3 = ld_b128u_sc(src + 12);
        waitcnt0();
        unsigned d = 0;
#pragma unroll
        for (int q2 = 0; q2 < 4; ++q2) {
          d |= (a0[q2] >> 16) ^ want; d |= (a1[q2] >> 16) ^ want;
          d |= (a2[q2] >> 16) ^ want; d |= (a3[q2] >> 16) ^ want;
        }
        if (d == 0) break;  // per-lane early exit
      }
      plo[0]=(short)a0[0]; plo[1]=(short)a0[1]; plo[2]=(short)a0[2]; plo[3]=(short)a0[3];
      plo[4]=(short)a1[0]; plo[5]=(short)a1[1]; plo[6]=(short)a1[2]; plo[7]=(short)a1[3];
      phi[0]=(short)a2[0]; phi[1]=(short)a2[1]; phi[2]=(short)a2[2]; phi[3]=(short)a2[3];
      phi[4]=(short)a3[0]; phi[5]=(short)a3[1]; phi[6]=(short)a3[2]; phi[7]=(short)a3[3];
    }
    // xg loads issued now; consumed after MFMA -> latency hidden
    float xc[2][4];
#pragma unroll
    for (int mt = 0; mt < 2; ++mt)
#pragma unroll
      for (int q = 0; q < 4; ++q)
        xc[mt][q] = xg[(it * 32 + mt * 16 + rq + q) * 2048 + wrow];

    *(short8*)&hbuf[sw_b * 512 + ((sw_x0 ^ sw_swz) * 8)] = plo;
    *(short8*)&hbuf[sw_b * 512 + (((sw_x0 + 1) ^ sw_swz) * 8)] = phi;
    __syncthreads();   // S1: hbuf ready (also orders hloc reads before C)

    // ---- (B) MFMA: gates = h_prev @ W_hh^T ----
    f32x4 acc0 = (f32x4){0.f, 0.f, 0.f, 0.f};
    f32x4 acc1 = (f32x4){0.f, 0.f, 0.f, 0.f};
#pragma unroll
    for (int kt = 0; kt < 16; ++kt) {
      int x = ((kt * 4 + (l >> 4)) ^ s0) * 8;
      short8 a0 = *(const short8*)&hbuf[b0 * 512 + x];
      short8 a1 = *(const short8*)&hbuf[b1 * 512 + x];
      acc0 = __builtin_amdgcn_mfma_f32_16x16x32_bf16(a0, bfr[kt], acc0, 0, 0, 0);
      acc1 = __builtin_amdgcn_mfma_f32_16x16x32_bf16(a1, bfr[kt], acc1, 0, 0, 0);
    }

    // ---- (C) pointwise LSTM cell -> hloc ----
#pragma unroll
    for (int mt = 0; mt < 2; ++mt) {
#pragma unroll
      for (int q = 0; q < 4; ++q) {
        float av = (mt == 0) ? acc0[q] : acc1[q];
        float gp = av + xc[mt][q];
        int bl = (l & 48) | jj;
        float xi = __shfl(gp, bl);
        float xf = __shfl(gp, bl | 4);
        float xgg = __shfl(gp, bl | 8);
        float xo = __shfl(gp, bl | 12);
        float is = 1.f / (1.f + __expf(-xi));
        float fs = 1.f / (1.f + __expf(-xf));
        float e2 = __expf(2.f * xgg);
        float gt = 1.f - 2.f / (e2 + 1.f);       // tanh, inf-safe
        float os = 1.f / (1.f + __expf(-xo));
        float cn = fs * creg[mt][q] + is * gt;
        creg[mt][q] = cn;
        float e2c = __expf(2.f * cn);
        float hn = os * (1.f - 2.f / (e2c + 1.f));
        if ((l & 12) == 0) {  // unique (b, j) writer lanes
          int b = mt * 16 + rq + q;
          hloc[b * 64 + w * 4 + jj] = f2bf(hn);
        }
      }
    }
    __syncthreads();   // S2: hloc complete; hbuf reads complete

    // ---- (D) publish: tagged sc-store (tid<512) + plain h2 (tid>=512) ----
    if (tid < 512) {
      if (it < 63) {
        u32 tag = ((u32)(it + 2)) << 16;
        u32x4 o;
        o[0] = tag | (u32)hloc[pb * 64 + pj4 + 0];
        o[1] = tag | (u32)hloc[pb * 64 + pj4 + 1];
        o[2] = tag | (u32)hloc[pb * 64 + pj4 + 2];
        o[3] = tag | (u32)hloc[pb * 64 + pj4 + 3];
        st_b128u_sc(htag + (it + 1) * 16384 + blk * 2048 + pb * 64 + pj4, o);
      }
    } else {
      u32 lo2 = ((u32)hloc[pb * 64 + pj4 + 1] << 16) | (u32)hloc[pb * 64 + pj4 + 0];
      u32 hi2 = ((u32)hloc[pb * 64 + pj4 + 3] << 16) | (u32)hloc[pb * 64 + pj4 + 2];
      u32x2 v2; v2[0] = lo2; v2[1] = hi2;
      *(u32x2*)&h2u[(it + 1) * 8192 + pb * 256 + blk * 32 + (pj4 >> 1)] = v2;
    }
    // no trailing barrier: next step's S1 orders hloc/hbuf reuse
  }
}

extern "C" void kernel_launch(void* const* d_in, const int* in_sizes, int n_in,
                              void* d_out, int out_size, void* d_ws, size_t ws_size,
                              hipStream_t stream) {
  (void)in_sizes; (void)n_in; (void)out_size; (void)ws_size;
  const float* iseq = (const float*)d_in[0];
  const float* h0   = (const float*)d_in[1];
  const float* wih  = (const float*)d_in[2];
  const float* whh  = (const float*)d_in[3];
  const float* bih  = (const float*)d_in[4];
  const float* bhh  = (const float*)d_in[5];
  const float* wout = (const float*)d_in[6];
  const float* bout = (const float*)d_in[7];

  char* ws = (char*)d_ws;
  u16* wout_bf = (u16*)(ws + 0);             // 32,768,000
  u16* wih_bf  = (u16*)(ws + 32768000);      // 2,097,152
  u16* whh_bf  = (u16*)(ws + 34865152);      // 2,097,152
  u16* ax      = (u16*)(ws + 36962304);      // 2,097,152
  u16* h2      = (u16*)(ws + 39059456);      // 65 slots x 32,768 = 2,129,920
  u32* htag    = (u32*)(ws + 41189376);      // 64 slots x 65,536 = 4,194,304
  float* xg    = (float*)(ws + 45383680);    // 16,777,216  (end 62,160,896)
  float* out   = (float*)d_out;

  prep_kernel<<<4096, 256, 0, stream>>>(iseq, h0, wih, whh, wout,
                                        wout_bf, wih_bf, whh_bf, ax,
                                        htag, (u32*)h2);
  // x_gates = A_x @ W_ih^T + b_ih + b_hh   -> xg [2048][2048] f32
  gemm_bt<<<dim3(16, 16), 256, 0, stream>>>(ax, wih_bf, xg, bih, bhh, 2048, 0);
  // persistent recurrence: 1-hop tagged exchange, 64 steps
  lstm_persist<<<LSTM_NBLK, 1024, 0, stream>>>(whh_bf, xg, h2, htag);
  // logits = h @ W_out^T + b_out -> d_out [2048][32000] f32 (A remapped from h2 slots)
  gemm_bt<<<dim3(250, 16), 256, 0, stream>>>(h2, wout_bf, out, bout, nullptr, 32000, 1);
}

// Round 8
// 575.471 us; speedup vs baseline: 1.4037x; 1.4037x over previous
//
#include <hip/hip_runtime.h>
#include <hip/hip_bf16.h>

typedef unsigned short u16;
typedef unsigned int u32;
typedef __attribute__((ext_vector_type(4))) float f32x4;
typedef __attribute__((ext_vector_type(8))) short short8;
typedef __attribute__((ext_vector_type(4))) unsigned short u16x4;
typedef __attribute__((ext_vector_type(4))) unsigned int u32x4;

// B=32, T=64, I=H=512, V=32000, G=4H=2048, M=T*B=2048
#define LSTM_NBLK 16

static __device__ __forceinline__ u16 f2bf(float f) {
  union { float f; unsigned u; } v; v.f = f;
  unsigned r = v.u + 0x7FFFu + ((v.u >> 16) & 1u);
  return (u16)(r >> 16);
}

static __device__ __forceinline__ void gload_lds16(const void* g, void* l) {
  __builtin_amdgcn_global_load_lds(
      (const __attribute__((address_space(1))) unsigned int*)g,
      (__attribute__((address_space(3))) unsigned int*)l, 16, 0, 0);
}

// --- L3-coherent (cross-XCD) access helpers: bypass L1/L2 ---
static __device__ __forceinline__ short8 ld_b128_sc(const void* p) {
  short8 r;
  asm volatile("global_load_dwordx4 %0, %1, off sc0 sc1"
               : "=v"(r) : "v"(p) : "memory");
  return r;
}
static __device__ __forceinline__ unsigned ld_u32_sc_wait(const unsigned* p) {
  unsigned r;
  asm volatile("global_load_dword %0, %1, off sc0 sc1\n\ts_waitcnt vmcnt(0)"
               : "=v"(r) : "v"(p) : "memory");
  return r;
}
static __device__ __forceinline__ void st_u32_sc(void* p, unsigned v) {
  asm volatile("global_store_dword %0, %1, off sc0 sc1"
               :: "v"(p), "v"(v) : "memory");
}
static __device__ __forceinline__ void waitcnt0() {
  asm volatile("s_waitcnt vmcnt(0)" ::: "memory");
  __builtin_amdgcn_sched_barrier(0);
}

// ---------------- prep: casts + transpose + h2 slot0 + flag init ----------------
__global__ void prep_kernel(const float* __restrict__ iseq, const float* __restrict__ h0,
                            const float* __restrict__ wih, const float* __restrict__ whh,
                            const float* __restrict__ wout,
                            u16* __restrict__ wout_bf, u16* __restrict__ wih_bf,
                            u16* __restrict__ whh_bf, u16* __restrict__ ax,
                            u32* __restrict__ h2u, unsigned* __restrict__ flags) {
  const int S0 = 4096000;                 // Wout /4
  const int S1 = S0 + 262144;             // Wih /4
  const int S2 = S1 + 262144;             // Whh /4
  const int S3 = S2 + 262144;             // ax /4
  const int S4 = S3 + 8192;               // h2 slot 0 (8192 u32)
  const int S5 = S4 + 4096;               // flags 16x16, 64B-padded (4096 u32)
  int u = blockIdx.x * blockDim.x + threadIdx.x;
  int stride = gridDim.x * blockDim.x;
  for (; u < S5; u += stride) {
    if (u < S0) {
      int e = u * 4; f32x4 v = *(const f32x4*)(wout + e);
      u16x4 o; o[0]=f2bf(v[0]); o[1]=f2bf(v[1]); o[2]=f2bf(v[2]); o[3]=f2bf(v[3]);
      *(u16x4*)(wout_bf + e) = o;
    } else if (u < S1) {
      int e = (u - S0) * 4; f32x4 v = *(const f32x4*)(wih + e);
      u16x4 o; o[0]=f2bf(v[0]); o[1]=f2bf(v[1]); o[2]=f2bf(v[2]); o[3]=f2bf(v[3]);
      *(u16x4*)(wih_bf + e) = o;
    } else if (u < S2) {
      int e = (u - S1) * 4; f32x4 v = *(const f32x4*)(whh + e);
      u16x4 o; o[0]=f2bf(v[0]); o[1]=f2bf(v[1]); o[2]=f2bf(v[2]); o[3]=f2bf(v[3]);
      *(u16x4*)(whh_bf + e) = o;
    } else if (u < S3) {
      // A_x[m= t*32+b][k] = iseq[b][t][k]
      int e = (u - S2) * 4; int m = e >> 9; int k = e & 511;
      int b = m & 31; int t = m >> 5;
      f32x4 v = *(const f32x4*)(iseq + ((b * 64 + t) << 9) + k);
      u16x4 o; o[0]=f2bf(v[0]); o[1]=f2bf(v[1]); o[2]=f2bf(v[2]); o[3]=f2bf(v[3]);
      *(u16x4*)(ax + e) = o;
    } else if (u < S4) {
      // h2 slot 0 = bf16(h0), [32][512] u16 packed as u32 pairs
      int v = u - S3;                    // 0..8191
      int e = v * 2;                     // f32 element index into h0
      float lo = h0[e], hi = h0[e + 1];
      h2u[v] = (((u32)f2bf(hi)) << 16) | (u32)f2bf(lo);
    } else {
      flags[u - S4] = 0u;
    }
  }
}

// ---------------- generic C = A*Bw^T + bias GEMM ----------------
// A: [2048][512] bf16 row-major (remap=0) or h2-slot layout (remap=1),
// Bw: [N][512] bf16 row-major, C: [2048][N] f32
__global__ __launch_bounds__(256, 2) void gemm_bt(
    const u16* __restrict__ A, const u16* __restrict__ Bw,
    float* __restrict__ C, const float* __restrict__ bias1,
    const float* __restrict__ bias2, int N, int remap) {
  __shared__ u16 As[2][8192];
  __shared__ u16 Bs[2][8192];
  const int tid = threadIdx.x;
  const int w = tid >> 6, l = tid & 63;
  const int wr = w >> 1, wc = w & 1;
  const int tm = blockIdx.y * 128, tn = blockIdx.x * 128;

  f32x4 acc[4][4];
#pragma unroll
  for (int i = 0; i < 4; ++i)
#pragma unroll
    for (int j = 0; j < 4; ++j) acc[i][j] = (f32x4){0.f, 0.f, 0.f, 0.f};

  auto stage = [&](int buf, int kt) {
#pragma unroll
    for (int i = 0; i < 4; ++i) {
      int r = (w * 4 + i) * 8 + (l >> 3);
      int c16 = (l & 7) ^ (r & 7);  // pre-swizzled source column
      int rowm = tm + r;
      const u16* srca;
      if (remap) {
        // logical A row m -> h_t[b] : slot (m&63)+1, row m>>6
        srca = A + ((rowm & 63) + 1) * 16384 + (rowm >> 6) * 512 + kt * 64 + c16 * 8;
      } else {
        srca = A + rowm * 512 + kt * 64 + c16 * 8;
      }
      gload_lds16(srca, &As[buf][(w * 4 + i) * 512]);
      const u16* srcb = Bw + (tn + r) * 512 + kt * 64 + c16 * 8;
      gload_lds16(srcb, &Bs[buf][(w * 4 + i) * 512]);
    }
  };

  stage(0, 0);
  int buf = 0;
  for (int kt = 0; kt < 8; ++kt) {
    __syncthreads();
    if (kt < 7) stage(buf ^ 1, kt + 1);
#pragma unroll
    for (int kk = 0; kk < 2; ++kk) {
      short8 af[4], bfr[4];
#pragma unroll
      for (int mi = 0; mi < 4; ++mi) {
        int row = wr * 64 + mi * 16 + (l & 15);
        int s = (kk * 4 + (l >> 4)) ^ (row & 7);
        af[mi] = *(const short8*)&As[buf][row * 64 + s * 8];
      }
#pragma unroll
      for (int ni = 0; ni < 4; ++ni) {
        int row = wc * 64 + ni * 16 + (l & 15);
        int s = (kk * 4 + (l >> 4)) ^ (row & 7);
        bfr[ni] = *(const short8*)&Bs[buf][row * 64 + s * 8];
      }
#pragma unroll
      for (int mi = 0; mi < 4; ++mi)
#pragma unroll
        for (int ni = 0; ni < 4; ++ni)
          acc[mi][ni] = __builtin_amdgcn_mfma_f32_16x16x32_bf16(
              af[mi], bfr[ni], acc[mi][ni], 0, 0, 0);
    }
    buf ^= 1;
  }

#pragma unroll
  for (int ni = 0; ni < 4; ++ni) {
    int gcol = tn + wc * 64 + ni * 16 + (l & 15);
    float bv = 0.f;
    if (bias1) bv += bias1[gcol];
    if (bias2) bv += bias2[gcol];
#pragma unroll
    for (int mi = 0; mi < 4; ++mi) {
      int grow0 = tm + wr * 64 + mi * 16 + ((l >> 4) << 2);
      f32x4 a = acc[mi][ni];
#pragma unroll
      for (int q = 0; q < 4; ++q) {
        C[(long long)(grow0 + q) * N + gcol] = a[q] + bv;
      }
    }
  }
}

// ---------------- persistent LSTM recurrence (block-granular exchange) ----------------
// Round-4 protocol (measured best: 6.3us/step) with ONE change: each
// (consumer, producer) flag lives on its own 64B line (flags[c*256+p*16]) so
// every coherent line in the protocol has exactly 1 writer and 1 reader —
// no partial-line RMW serialization on the flag hop.
__global__ __launch_bounds__(512, 1) void lstm_persist(
    const u16* __restrict__ whh, const float* __restrict__ xg,
    u16* __restrict__ h2, unsigned* __restrict__ flags) {
  __shared__ u16 hbuf[32 * 512];
  __shared__ u16 hloc[1024];
  const int tid = threadIdx.x;
  const int w = tid >> 6, l = tid & 63;
  const int blk = blockIdx.x;
  const int j0 = (blk * 8 + w) * 4;                // wave's 4 h-columns
  const int c = l & 15;
  const int wrow = (c >> 2) * 512 + j0 + (c & 3);  // W_hh row == gate column
  const int ko = (l >> 4) * 8;
  u32* h2u = (u32*)h2;

  // resident weights: 16 x short8 = 64 VGPRs
  short8 bfr[16];
  const u16* wp = whh + wrow * 512 + ko;
#pragma unroll
  for (int kt = 0; kt < 16; ++kt) bfr[kt] = *(const short8*)(wp + kt * 32);

  const int rq = (l >> 4) * 4;
  const int jj = l & 3;
  const int b0 = l & 15, b1 = 16 + (l & 15);
  const int s0 = b0 & 7;

  // consumer stage mapping: thread covers (row cb, 32 k starting ckg*32)
  const int cb = tid & 31;
  const int ckg = tid >> 5;        // 0..15
  const int csw = cb & 7;

  // hloc -> h2 publish mapping: thread stores (row ob, u32 col oj)
  const int ob = tid >> 4;         // 0..31
  const int oj = tid & 15;         // 0..15

  float creg[2][4];
#pragma unroll
  for (int mt = 0; mt < 2; ++mt)
#pragma unroll
    for (int q = 0; q < 4; ++q) creg[mt][q] = 0.f;

  float xcur[2][4], xnext[2][4];
#pragma unroll
  for (int mt = 0; mt < 2; ++mt)
#pragma unroll
    for (int q = 0; q < 4; ++q)
      xcur[mt][q] = xg[(mt * 16 + rq + q) * 2048 + wrow];

  for (int it = 0; it < 64; ++it) {
    // ---- (A) gate: wave0 polls 16 private flag lines (1 writer/1 reader each) ----
    if (it > 0 && w == 0) {
      const unsigned want = (unsigned)it;
      for (;;) {
        unsigned f = ld_u32_sc_wait(flags + blk * 256 + (l & 15) * 16);
        if (__all((int)(f >= want))) break;
      }
    }
    __syncthreads();

    // ---- (B) stage slot[it] -> XOR-swizzled LDS ----
    {
      const u16* src = h2 + it * 16384 + cb * 512 + ckg * 32;
      short8 d0 = ld_b128_sc(src);
      short8 d1 = ld_b128_sc(src + 8);
      short8 d2 = ld_b128_sc(src + 16);
      short8 d3 = ld_b128_sc(src + 24);
      waitcnt0();
      *(short8*)&hbuf[cb * 512 + (((ckg * 4 + 0) ^ csw) * 8)] = d0;
      *(short8*)&hbuf[cb * 512 + (((ckg * 4 + 1) ^ csw) * 8)] = d1;
      *(short8*)&hbuf[cb * 512 + (((ckg * 4 + 2) ^ csw) * 8)] = d2;
      *(short8*)&hbuf[cb * 512 + (((ckg * 4 + 3) ^ csw) * 8)] = d3;
    }
    __syncthreads();

    // ---- (C) MFMA: gates = h_{prev} @ W_hh^T ----
    f32x4 acc0 = (f32x4){0.f, 0.f, 0.f, 0.f};
    f32x4 acc1 = (f32x4){0.f, 0.f, 0.f, 0.f};
#pragma unroll
    for (int kt = 0; kt < 16; ++kt) {
      int x = ((kt * 4 + (l >> 4)) ^ s0) * 8;
      short8 a0 = *(const short8*)&hbuf[b0 * 512 + x];
      short8 a1 = *(const short8*)&hbuf[b1 * 512 + x];
      acc0 = __builtin_amdgcn_mfma_f32_16x16x32_bf16(a0, bfr[kt], acc0, 0, 0, 0);
      acc1 = __builtin_amdgcn_mfma_f32_16x16x32_bf16(a1, bfr[kt], acc1, 0, 0, 0);
    }
    // xg prefetch for it+1 hides under MFMA/pointwise
    if (it < 63) {
#pragma unroll
      for (int mt = 0; mt < 2; ++mt)
#pragma unroll
        for (int q = 0; q < 4; ++q)
          xnext[mt][q] = xg[((it + 1) * 32 + mt * 16 + rq + q) * 2048 + wrow];
    }

    // ---- (D) pointwise LSTM cell -> hloc ----
#pragma unroll
    for (int mt = 0; mt < 2; ++mt) {
#pragma unroll
      for (int q = 0; q < 4; ++q) {
        float av = (mt == 0) ? acc0[q] : acc1[q];
        float gp = av + xcur[mt][q];
        int bl = (l & 48) | jj;
        float xi = __shfl(gp, bl);
        float xf = __shfl(gp, bl | 4);
        float xgg = __shfl(gp, bl | 8);
        float xo = __shfl(gp, bl | 12);
        float is = 1.f / (1.f + __expf(-xi));
        float fs = 1.f / (1.f + __expf(-xf));
        float e2 = __expf(2.f * xgg);
        float gt = 1.f - 2.f / (e2 + 1.f);       // tanh, inf-safe
        float os = 1.f / (1.f + __expf(-xo));
        float cn = fs * creg[mt][q] + is * gt;
        creg[mt][q] = cn;
        float e2c = __expf(2.f * cn);
        float hn = os * (1.f - 2.f / (e2c + 1.f));
        if ((l & 12) == 0) {  // unique (b, j) writer lanes
          int b = mt * 16 + rq + q;
          hloc[b * 32 + w * 4 + jj] = f2bf(hn);
        }
      }
    }
    __syncthreads();   // hloc complete

    // ---- (E) publish block slice -> slot[it+1], full-line dwords ----
    {
      u32 v = *(const u32*)&hloc[ob * 32 + oj * 2];
      st_u32_sc(h2u + (it + 1) * 8192 + ob * 256 + blk * 16 + oj, v);
      waitcnt0();
    }
    __syncthreads();

    // ---- (F) flag (own line per consumer) + xg rotate ----
    if (it < 63) {
      if (w == 0 && l < 16)
        st_u32_sc(flags + l * 256 + blk * 16, (unsigned)(it + 1));
#pragma unroll
      for (int mt = 0; mt < 2; ++mt)
#pragma unroll
        for (int q = 0; q < 4; ++q)
          xcur[mt][q] = xnext[mt][q];
    }
  }
}

extern "C" void kernel_launch(void* const* d_in, const int* in_sizes, int n_in,
                              void* d_out, int out_size, void* d_ws, size_t ws_size,
                              hipStream_t stream) {
  (void)in_sizes; (void)n_in; (void)out_size; (void)ws_size;
  const float* iseq = (const float*)d_in[0];
  const float* h0   = (const float*)d_in[1];
  const float* wih  = (const float*)d_in[2];
  const float* whh  = (const float*)d_in[3];
  const float* bih  = (const float*)d_in[4];
  const float* bhh  = (const float*)d_in[5];
  const float* wout = (const float*)d_in[6];
  const float* bout = (const float*)d_in[7];

  char* ws = (char*)d_ws;
  u16* wout_bf = (u16*)(ws + 0);             // 32,768,000
  u16* wih_bf  = (u16*)(ws + 32768000);      // 2,097,152
  u16* whh_bf  = (u16*)(ws + 34865152);      // 2,097,152
  u16* ax      = (u16*)(ws + 36962304);      // 2,097,152
  u16* h2      = (u16*)(ws + 39059456);      // 65 slots x 32,768 = 2,129,920
  unsigned* flags = (unsigned*)(ws + 41189376); // 16,384 (16x16, 64B-padded)
  float* xg    = (float*)(ws + 41254912);    // 16,777,216  (end 58,032,128)
  float* out   = (float*)d_out;

  prep_kernel<<<4096, 256, 0, stream>>>(iseq, h0, wih, whh, wout,
                                        wout_bf, wih_bf, whh_bf, ax,
                                        (u32*)h2, flags);
  // x_gates = A_x @ W_ih^T + b_ih + b_hh   -> xg [2048][2048] f32
  gemm_bt<<<dim3(16, 16), 256, 0, stream>>>(ax, wih_bf, xg, bih, bhh, 2048, 0);
  // persistent recurrence: block-granular exchange, padded flags, 64 steps
  lstm_persist<<<LSTM_NBLK, 512, 0, stream>>>(whh_bf, xg, h2, flags);
  // logits = h @ W_out^T + b_out -> d_out [2048][32000] f32 (A remapped from h2 slots)
  gemm_bt<<<dim3(250, 16), 256, 0, stream>>>(h2, wout_bf, out, bout, nullptr, 32000, 1);
}